// Round 1
// baseline (687.149 us; speedup 1.0000x reference)
//
#include <hip/hip_runtime.h>

// ---------------------------------------------------------------------------
// Attention (Bahdanau): B=32, S=2048, H=512, 2H=1024, 4H=2048
//   u[b,h]      = bias[h] + dot(hidden[b,:1024], W[h,:1024])      (fp32, tiny)
//   scores[b,s] = sum_h v[h]*tanh(u[b,h] + dot(enc[b,s,:], W[h,1024:]))
//   attn        = softmax_s(scores);  context[b,d] = sum_s attn[b,s]*enc[b,s,d]
// Main GEMM done with bf16 MFMA 16x16x32 using hi/lo split (3 MFMAs) for
// ~fp32 accuracy. W2 pre-packed to bf16 hi/lo in fragment-major layout so the
// score kernel stages B with global_load_lds (width 16).
// ---------------------------------------------------------------------------

typedef __attribute__((ext_vector_type(8))) short short8;
typedef __attribute__((ext_vector_type(4))) float f4;

__device__ __forceinline__ unsigned short bf16_rn(float x) {
    unsigned int u = __float_as_uint(x);
    return (unsigned short)((u + 0x7FFFu + ((u >> 16) & 1u)) >> 16);
}
__device__ __forceinline__ float bf16_to_f(unsigned short h) {
    return __uint_as_float(((unsigned int)h) << 16);
}
__device__ __forceinline__ void gload_lds16(const void* g, void* l) {
    __builtin_amdgcn_global_load_lds(
        (const __attribute__((address_space(1))) unsigned int*)g,
        (__attribute__((address_space(3))) unsigned int*)l, 16, 0, 0);
}

// ---------------------------------------------------------------------------
// Kernel 1: u[b,h] (blocks 0..63) + W2 bf16 hi/lo fragment-major pack (64..319)
// Pack layout: chunk g = kk*2048 + (nt*4+q)*16 + c  holds
//   W[h=nt*16+c][1024 + kk*32 + q*8 + j], j=0..7  (8 bf16 = 16B)
// ---------------------------------------------------------------------------
__global__ __launch_bounds__(256) void prep_kernel(
    const float* __restrict__ hidden, const float* __restrict__ W,
    const float* __restrict__ bias, float* __restrict__ u,
    unsigned short* __restrict__ w2hi, unsigned short* __restrict__ w2lo) {
    if (blockIdx.x < 64) {
        int t = blockIdx.x * 256 + threadIdx.x;   // 0..16383
        int b = t >> 9, h = t & 511;
        const f4* wr = (const f4*)(W + (size_t)h * 2048);
        const f4* hr = (const f4*)(hidden + (size_t)b * 1024);
        float acc = bias[h];
        #pragma unroll 4
        for (int i = 0; i < 256; ++i) {
            f4 w4 = wr[i]; f4 h4 = hr[i];
            acc += w4[0]*h4[0] + w4[1]*h4[1] + w4[2]*h4[2] + w4[3]*h4[3];
        }
        u[t] = acc;
    } else {
        int g = (blockIdx.x - 64) * 256 + threadIdx.x;   // 0..65535 chunks
        int kk = g >> 11, id = g & 2047;
        int nt = id >> 6, q = (id >> 4) & 3, c = id & 15;
        int h = nt * 16 + c;
        const float* src = W + (size_t)h * 2048 + 1024 + kk * 32 + q * 8;
        short8 vhi, vlo;
        #pragma unroll
        for (int j = 0; j < 8; ++j) {
            float x = src[j];
            unsigned short hb = bf16_rn(x);
            unsigned short lb = bf16_rn(x - bf16_to_f(hb));
            vhi[j] = (short)hb; vlo[j] = (short)lb;
        }
        ((short8*)w2hi)[g] = vhi;
        ((short8*)w2lo)[g] = vlo;
    }
}

// ---------------------------------------------------------------------------
// Kernel 2: fused scores. Block = 64 s-rows x 512 h, 512 threads (8 waves).
// Wave wl covers h in [wl*64, wl*64+64): 4 m-tiles x 4 n-tiles, 3 MFMAs each.
// ---------------------------------------------------------------------------
__global__ __launch_bounds__(512, 2) void score_kernel(
    const float* __restrict__ enc, const unsigned short* __restrict__ w2hi,
    const unsigned short* __restrict__ w2lo, const float* __restrict__ u,
    const float* __restrict__ v, float* __restrict__ scores) {
    __shared__ short Ahi[2048], Alo[2048];     // 64 rows x 32 k, chunk-major
    __shared__ short Bhi[16384], Blo[16384];   // 512 h x 32 k, chunk-major
    __shared__ float u_s[512], v_s[512];
    __shared__ float partial[8][64];

    const int tid  = threadIdx.x;
    const int wl   = tid >> 6, lane = tid & 63;
    const int q    = lane >> 4, m = lane & 15;
    const int row0 = blockIdx.x * 64;
    const int b    = row0 >> 11;
    const float* encB = enc + (size_t)row0 * 1024;

    u_s[tid < 512 ? tid : 0] = u[(b << 9) + tid];
    v_s[tid] = v[tid];

    f4 acc[4][4];
    #pragma unroll
    for (int mt = 0; mt < 4; ++mt)
        #pragma unroll
        for (int nt = 0; nt < 4; ++nt) acc[mt][nt] = (f4){0.f, 0.f, 0.f, 0.f};

    for (int kk = 0; kk < 32; ++kk) {
        __syncthreads();
        // --- stage A (enc) fp32 -> bf16 hi/lo, threads 0..255, 1 chunk each
        if (tid < 256) {
            const int amt = tid >> 6, aq = (tid >> 4) & 3, ac = tid & 15;
            const float* s0 = encB + (size_t)((amt << 4) + ac) * 1024 + (kk << 5) + (aq << 3);
            f4 x0 = *(const f4*)s0;
            f4 x1 = *(const f4*)(s0 + 4);
            short8 vhi, vlo;
            #pragma unroll
            for (int j = 0; j < 4; ++j) {
                unsigned short hb = bf16_rn(x0[j]);
                vhi[j] = (short)hb; vlo[j] = (short)bf16_rn(x0[j] - bf16_to_f(hb));
            }
            #pragma unroll
            for (int j = 0; j < 4; ++j) {
                unsigned short hb = bf16_rn(x1[j]);
                vhi[4+j] = (short)hb; vlo[4+j] = (short)bf16_rn(x1[j] - bf16_to_f(hb));
            }
            ((short8*)Ahi)[tid] = vhi;
            ((short8*)Alo)[tid] = vlo;
        }
        // --- stage B (W2 packed bf16) via global_load_lds, 32KB hi + 32KB lo
        {
            const size_t stepOff = (size_t)kk * 32768;   // bytes per K-step
            #pragma unroll
            for (int i = 0; i < 4; ++i) {
                unsigned int off = (unsigned int)((wl * 4 + i) << 10);   // bytes
                gload_lds16((const char*)w2hi + stepOff + off + lane * 16,
                            (char*)Bhi + off);
                gload_lds16((const char*)w2lo + stepOff + off + lane * 16,
                            (char*)Blo + off);
            }
        }
        __syncthreads();
        // --- compute
        short8 ah[4], al[4];
        #pragma unroll
        for (int mt = 0; mt < 4; ++mt) {
            int idx = ((mt * 4 + q) << 4) + m;
            ah[mt] = ((short8*)Ahi)[idx];
            al[mt] = ((short8*)Alo)[idx];
        }
        #pragma unroll
        for (int nt = 0; nt < 4; ++nt) {
            int bidx = (((wl * 4 + nt) * 4 + q) << 4) + m;
            short8 bh = ((short8*)Bhi)[bidx];
            short8 bl = ((short8*)Blo)[bidx];
            #pragma unroll
            for (int mt = 0; mt < 4; ++mt) {
                acc[mt][nt] = __builtin_amdgcn_mfma_f32_16x16x32_bf16(ah[mt], bh, acc[mt][nt], 0, 0, 0);
                acc[mt][nt] = __builtin_amdgcn_mfma_f32_16x16x32_bf16(ah[mt], bl, acc[mt][nt], 0, 0, 0);
                acc[mt][nt] = __builtin_amdgcn_mfma_f32_16x16x32_bf16(al[mt], bh, acc[mt][nt], 0, 0, 0);
            }
        }
    }
    // --- epilogue: tanh, v-weight, reduce over h
    #pragma unroll
    for (int mt = 0; mt < 4; ++mt) {
        #pragma unroll
        for (int reg = 0; reg < 4; ++reg) {
            float ssum = 0.f;
            #pragma unroll
            for (int nt = 0; nt < 4; ++nt) {
                int h = (wl << 6) + (nt << 4) + m;
                float e = tanhf(u_s[h] + acc[mt][nt][reg]);
                ssum += v_s[h] * e;
            }
            ssum += __shfl_xor(ssum, 1);
            ssum += __shfl_xor(ssum, 2);
            ssum += __shfl_xor(ssum, 4);
            ssum += __shfl_xor(ssum, 8);
            if (m == 0) partial[wl][(mt << 4) + (q << 2) + reg] = ssum;
        }
    }
    __syncthreads();
    if (tid < 64) {
        float s = 0.f;
        #pragma unroll
        for (int w = 0; w < 8; ++w) s += partial[w][tid];
        scores[row0 + tid] = s;
    }
}

// ---------------------------------------------------------------------------
// Kernel 3: per-(b, s-chunk) softmax + partial context (no atomics)
// ---------------------------------------------------------------------------
__global__ __launch_bounds__(256) void ctx_partial_kernel(
    const float* __restrict__ enc, const float* __restrict__ scores,
    float* __restrict__ partials) {
    __shared__ float p_s[2048];
    __shared__ float wredm[4], wreds[4];
    const int t = threadIdx.x;
    const int b = blockIdx.x >> 3, sc = blockIdx.x & 7;
    const int wid = t >> 6, lane = t & 63;
    const float* srow = scores + ((size_t)b << 11);

    float vals[8];
    float mx = -1e30f;
    #pragma unroll
    for (int i = 0; i < 8; ++i) { vals[i] = srow[t + (i << 8)]; mx = fmaxf(mx, vals[i]); }
    #pragma unroll
    for (int off = 1; off < 64; off <<= 1) mx = fmaxf(mx, __shfl_xor(mx, off));
    if (lane == 0) wredm[wid] = mx;
    __syncthreads();
    mx = fmaxf(fmaxf(wredm[0], wredm[1]), fmaxf(wredm[2], wredm[3]));

    float lsum = 0.f;
    #pragma unroll
    for (int i = 0; i < 8; ++i) {
        float e = __expf(vals[i] - mx);
        p_s[t + (i << 8)] = e;
        lsum += e;
    }
    #pragma unroll
    for (int off = 1; off < 64; off <<= 1) lsum += __shfl_xor(lsum, off);
    if (lane == 0) wreds[wid] = lsum;
    __syncthreads();
    const float inv = 1.f / (wreds[0] + wreds[1] + wreds[2] + wreds[3]);

    f4 a = (f4){0.f, 0.f, 0.f, 0.f};
    const f4* erow = ((const f4*)(enc + (((size_t)b * 2048 + (sc << 8)) << 10))) + t;
    #pragma unroll 4
    for (int i = 0; i < 256; ++i) {
        float p = p_s[(sc << 8) + i] * inv;
        f4 e = erow[(size_t)i << 8];
        a += p * e;
    }
    f4* dst = (f4*)(partials + (((size_t)(sc << 5) + b) << 10));
    dst[t] = a;
}

// ---------------------------------------------------------------------------
// Kernel 4: reduce 8 s-chunk partials -> context
// ---------------------------------------------------------------------------
__global__ __launch_bounds__(256) void ctx_reduce_kernel(
    const float* __restrict__ partials, float* __restrict__ out) {
    int i = blockIdx.x * 256 + threadIdx.x;   // 0..32767  (b*1024 + d)
    float s = 0.f;
    #pragma unroll
    for (int sc = 0; sc < 8; ++sc) s += partials[sc * 32768 + i];
    out[i] = s;
}

// ---------------------------------------------------------------------------
extern "C" void kernel_launch(void* const* d_in, const int* in_sizes, int n_in,
                              void* d_out, int out_size, void* d_ws, size_t ws_size,
                              hipStream_t stream) {
    const float* hidden = (const float*)d_in[0];   // [32,1024]
    const float* enc    = (const float*)d_in[1];   // [32,2048,1024]
    const float* W      = (const float*)d_in[2];   // [512,2048]
    const float* bias   = (const float*)d_in[3];   // [512]
    const float* v      = (const float*)d_in[4];   // [512]
    float* out = (float*)d_out;                    // [32,1024]
    char* ws = (char*)d_ws;

    // ws layout (bytes):
    float* u              = (float*)(ws);                    //  65536
    float* scores         = (float*)(ws + 65536);            // 262144
    float* partials       = (float*)(ws + 327680);           // 1048576
    unsigned short* w2hi  = (unsigned short*)(ws + 1376256); // 1048576
    unsigned short* w2lo  = (unsigned short*)(ws + 2424832); // 1048576  (total ~3.4MB)

    prep_kernel<<<320, 256, 0, stream>>>(hidden, W, bias, u, w2hi, w2lo);
    score_kernel<<<1024, 512, 0, stream>>>(enc, w2hi, w2lo, u, v, scores);
    ctx_partial_kernel<<<256, 256, 0, stream>>>(enc, scores, partials);
    ctx_reduce_kernel<<<128, 256, 0, stream>>>(partials, out);
}

// Round 2
// 592.276 us; speedup vs baseline: 1.1602x; 1.1602x over previous
//
#include <hip/hip_runtime.h>

// ---------------------------------------------------------------------------
// Attention (Bahdanau): B=32, S=2048, H=512, 2H=1024, 4H=2048
//   u[b,h]      = bias[h] + dot(hidden[b,:1024], W[h,:1024])      (fp32, tiny)
//   scores[b,s] = sum_h v[h]*tanh(u[b,h] + dot(enc[b,s,:], W[h,1024:]))
//   attn        = softmax_s(scores);  context[b,d] = sum_s attn[b,s]*enc[b,s,d]
// bf16 MFMA 16x16x32 with hi/lo split (3 MFMAs) for ~fp32 accuracy.
// R2: h split into 2 halves/block (LDS 44KB -> 3 blocks/CU), 2048 score
// blocks; ctx_partial widened to 1024 blocks.
// ---------------------------------------------------------------------------

typedef __attribute__((ext_vector_type(8))) short short8;
typedef __attribute__((ext_vector_type(4))) short short4v;
typedef __attribute__((ext_vector_type(4))) float f4;

__device__ __forceinline__ unsigned short bf16_rn(float x) {
    unsigned int u = __float_as_uint(x);
    return (unsigned short)((u + 0x7FFFu + ((u >> 16) & 1u)) >> 16);
}
__device__ __forceinline__ float bf16_to_f(unsigned short h) {
    return __uint_as_float(((unsigned int)h) << 16);
}
__device__ __forceinline__ void gload_lds16(const void* g, void* l) {
    __builtin_amdgcn_global_load_lds(
        (const __attribute__((address_space(1))) unsigned int*)g,
        (__attribute__((address_space(3))) unsigned int*)l, 16, 0, 0);
}

// ---------------------------------------------------------------------------
// Kernel 1: u[b,h] (blocks 0..63) + W2 bf16 hi/lo fragment-major pack (64..319)
// Pack layout: chunk g = kk*2048 + nt*64 + q*16 + c  holds
//   W[h=nt*16+c][1024 + kk*32 + q*8 + j], j=0..7  (8 bf16 = 16B)
// ---------------------------------------------------------------------------
__global__ __launch_bounds__(256) void prep_kernel(
    const float* __restrict__ hidden, const float* __restrict__ W,
    const float* __restrict__ bias, float* __restrict__ u,
    unsigned short* __restrict__ w2hi, unsigned short* __restrict__ w2lo) {
    if (blockIdx.x < 64) {
        int t = blockIdx.x * 256 + threadIdx.x;   // 0..16383
        int b = t >> 9, h = t & 511;
        const f4* wr = (const f4*)(W + (size_t)h * 2048);
        const f4* hr = (const f4*)(hidden + (size_t)b * 1024);
        float acc = bias[h];
        #pragma unroll 4
        for (int i = 0; i < 256; ++i) {
            f4 w4 = wr[i]; f4 h4 = hr[i];
            acc += w4[0]*h4[0] + w4[1]*h4[1] + w4[2]*h4[2] + w4[3]*h4[3];
        }
        u[t] = acc;
    } else {
        int g = (blockIdx.x - 64) * 256 + threadIdx.x;   // 0..65535 chunks
        int kk = g >> 11, id = g & 2047;
        int nt = id >> 6, q = (id >> 4) & 3, c = id & 15;
        int h = nt * 16 + c;
        const float* src = W + (size_t)h * 2048 + 1024 + kk * 32 + q * 8;
        short8 vhi, vlo;
        #pragma unroll
        for (int j = 0; j < 8; ++j) {
            float x = src[j];
            unsigned short hb = bf16_rn(x);
            unsigned short lb = bf16_rn(x - bf16_to_f(hb));
            vhi[j] = (short)hb; vlo[j] = (short)lb;
        }
        ((short8*)w2hi)[g] = vhi;
        ((short8*)w2lo)[g] = vlo;
    }
}

// ---------------------------------------------------------------------------
// Kernel 2: fused partial scores. Block = 64 s-rows x 256 h (one h-half),
// 512 threads (8 waves). Wave wl covers local n-tiles {2wl, 2wl+1}.
// grid 2048: sblk = blockIdx.x>>1 (enc tile shared by hh pair), hh = &1.
// LDS = 4+4+16+16+1+1+2 = 44KB -> 3 blocks/CU.
// ---------------------------------------------------------------------------
__global__ __launch_bounds__(512, 6) void score_kernel(
    const float* __restrict__ enc, const unsigned short* __restrict__ w2hi,
    const unsigned short* __restrict__ w2lo, const float* __restrict__ u,
    const float* __restrict__ v, float* __restrict__ scores_part) {
    __shared__ short Ahi[2048], Alo[2048];     // 64 rows x 32 k, chunk-major
    __shared__ short Bhi[8192], Blo[8192];     // 256 h x 32 k, chunk-major
    __shared__ float u_s[256], v_s[256];
    __shared__ float partial[8][64];

    const int tid  = threadIdx.x;
    const int wl   = tid >> 6, lane = tid & 63;
    const int q    = lane >> 4, m = lane & 15;
    const int sblk = blockIdx.x >> 1, hh = blockIdx.x & 1;
    const int row0 = sblk * 64;
    const int b    = row0 >> 11;
    const float* encB = enc + (size_t)row0 * 1024;

    if (tid < 256) {
        u_s[tid] = u[(b << 9) + (hh << 8) + tid];
        v_s[tid] = v[(hh << 8) + tid];
    }

    f4 acc[4][2];
    #pragma unroll
    for (int mt = 0; mt < 4; ++mt)
        #pragma unroll
        for (int nt = 0; nt < 2; ++nt) acc[mt][nt] = (f4){0.f, 0.f, 0.f, 0.f};

    // A staging indices for this thread (half-chunk = 4 floats)
    const int c8   = tid >> 1, half = tid & 1;
    const int arow = ((c8 >> 6) << 4) + (c8 & 15);
    const int akof = (((c8 >> 4) & 3) << 3) + (half << 2);
    const float* aBase = encB + (size_t)arow * 1024 + akof;

    for (int kk = 0; kk < 32; ++kk) {
        __syncthreads();
        // --- stage A (enc) fp32 -> bf16 hi/lo, all 512 threads, 4 elems each
        {
            f4 x = *(const f4*)(aBase + (kk << 5));
            short4v vhi, vlo;
            #pragma unroll
            for (int j = 0; j < 4; ++j) {
                unsigned short hb = bf16_rn(x[j]);
                vhi[j] = (short)hb; vlo[j] = (short)bf16_rn(x[j] - bf16_to_f(hb));
            }
            ((short4v*)Ahi)[tid] = vhi;
            ((short4v*)Alo)[tid] = vlo;
        }
        // --- stage B (W2 packed bf16) via global_load_lds: 16KB hi + 16KB lo
        {
            const size_t srcOff = (size_t)kk * 32768 + (hh << 14) + (wl << 11) + lane * 16;
            #pragma unroll
            for (int i = 0; i < 2; ++i) {
                unsigned int off = (unsigned int)((wl << 11) + (i << 10));   // bytes
                gload_lds16((const char*)w2hi + srcOff + (i << 10), (char*)Bhi + off);
                gload_lds16((const char*)w2lo + srcOff + (i << 10), (char*)Blo + off);
            }
        }
        __syncthreads();
        // --- compute: 4 m-tiles x 2 n-tiles x 3 MFMAs
        short8 ah[4], al[4];
        #pragma unroll
        for (int mt = 0; mt < 4; ++mt) {
            int idx = (mt << 6) + (q << 4) + m;
            ah[mt] = ((short8*)Ahi)[idx];
            al[mt] = ((short8*)Alo)[idx];
        }
        #pragma unroll
        for (int nt = 0; nt < 2; ++nt) {
            int ntl = (wl << 1) + nt;
            int bidx = (ntl << 6) + (q << 4) + m;
            short8 bh = ((short8*)Bhi)[bidx];
            short8 bl = ((short8*)Blo)[bidx];
            #pragma unroll
            for (int mt = 0; mt < 4; ++mt) {
                acc[mt][nt] = __builtin_amdgcn_mfma_f32_16x16x32_bf16(ah[mt], bh, acc[mt][nt], 0, 0, 0);
                acc[mt][nt] = __builtin_amdgcn_mfma_f32_16x16x32_bf16(ah[mt], bl, acc[mt][nt], 0, 0, 0);
                acc[mt][nt] = __builtin_amdgcn_mfma_f32_16x16x32_bf16(al[mt], bh, acc[mt][nt], 0, 0, 0);
            }
        }
    }
    // --- epilogue: tanh, v-weight, reduce over local h (256)
    #pragma unroll
    for (int mt = 0; mt < 4; ++mt) {
        #pragma unroll
        for (int reg = 0; reg < 4; ++reg) {
            float ssum = 0.f;
            #pragma unroll
            for (int nt = 0; nt < 2; ++nt) {
                int hl = (wl << 5) + (nt << 4) + m;
                float e = tanhf(u_s[hl] + acc[mt][nt][reg]);
                ssum += v_s[hl] * e;
            }
            ssum += __shfl_xor(ssum, 1);
            ssum += __shfl_xor(ssum, 2);
            ssum += __shfl_xor(ssum, 4);
            ssum += __shfl_xor(ssum, 8);
            if (m == 0) partial[wl][(mt << 4) + (q << 2) + reg] = ssum;
        }
    }
    __syncthreads();
    if (tid < 64) {
        float s = 0.f;
        #pragma unroll
        for (int w = 0; w < 8; ++w) s += partial[w][tid];
        scores_part[(hh << 16) + row0 + tid] = s;
    }
}

// ---------------------------------------------------------------------------
// Kernel 3: per-(b, 64-row s-chunk) softmax + partial context, 1024 blocks
// ---------------------------------------------------------------------------
__global__ __launch_bounds__(256) void ctx_partial_kernel(
    const float* __restrict__ enc, const float* __restrict__ scores_part,
    float* __restrict__ partials) {
    __shared__ float p_s[2048];
    __shared__ float wredm[4], wreds[4];
    const int t = threadIdx.x;
    const int b = blockIdx.x >> 5, sc = blockIdx.x & 31;
    const int wid = t >> 6, lane = t & 63;
    const float* s0 = scores_part + ((size_t)b << 11);
    const float* s1 = s0 + 65536;

    float vals[8];
    float mx = -1e30f;
    #pragma unroll
    for (int i = 0; i < 8; ++i) {
        int idx = t + (i << 8);
        vals[i] = s0[idx] + s1[idx];
        mx = fmaxf(mx, vals[i]);
    }
    #pragma unroll
    for (int off = 1; off < 64; off <<= 1) mx = fmaxf(mx, __shfl_xor(mx, off));
    if (lane == 0) wredm[wid] = mx;
    __syncthreads();
    mx = fmaxf(fmaxf(wredm[0], wredm[1]), fmaxf(wredm[2], wredm[3]));

    float lsum = 0.f;
    #pragma unroll
    for (int i = 0; i < 8; ++i) {
        float e = __expf(vals[i] - mx);
        p_s[t + (i << 8)] = e;
        lsum += e;
    }
    #pragma unroll
    for (int off = 1; off < 64; off <<= 1) lsum += __shfl_xor(lsum, off);
    if (lane == 0) wreds[wid] = lsum;
    __syncthreads();
    const float inv = 1.f / (wreds[0] + wreds[1] + wreds[2] + wreds[3]);

    f4 a = (f4){0.f, 0.f, 0.f, 0.f};
    const f4* erow = ((const f4*)(enc + ((size_t)b * 2048 + (sc << 6)) * 1024)) + t;
    #pragma unroll 4
    for (int i = 0; i < 64; ++i) {
        float p = p_s[(sc << 6) + i] * inv;
        f4 e = erow[(size_t)i << 8];
        a += p * e;
    }
    f4* dst = (f4*)(partials + (((size_t)(sc << 5) + b) << 10));
    dst[t] = a;
}

// ---------------------------------------------------------------------------
// Kernel 4: reduce 32 s-chunk partials -> context
// ---------------------------------------------------------------------------
__global__ __launch_bounds__(256) void ctx_reduce_kernel(
    const float* __restrict__ partials, float* __restrict__ out) {
    int i = blockIdx.x * 256 + threadIdx.x;   // 0..32767  (b*1024 + d)
    float s = 0.f;
    #pragma unroll
    for (int sc = 0; sc < 32; ++sc) s += partials[sc * 32768 + i];
    out[i] = s;
}

// ---------------------------------------------------------------------------
extern "C" void kernel_launch(void* const* d_in, const int* in_sizes, int n_in,
                              void* d_out, int out_size, void* d_ws, size_t ws_size,
                              hipStream_t stream) {
    const float* hidden = (const float*)d_in[0];   // [32,1024]
    const float* enc    = (const float*)d_in[1];   // [32,2048,1024]
    const float* W      = (const float*)d_in[2];   // [512,2048]
    const float* bias   = (const float*)d_in[3];   // [512]
    const float* v      = (const float*)d_in[4];   // [512]
    float* out = (float*)d_out;                    // [32,1024]
    char* ws = (char*)d_ws;

    // ws layout (bytes):
    float* u              = (float*)(ws);                    //    65536
    float* scores_part    = (float*)(ws + 65536);            //   524288 (2 halves)
    float* partials       = (float*)(ws + 589824);           //  4194304
    unsigned short* w2hi  = (unsigned short*)(ws + 4784128); //  1048576
    unsigned short* w2lo  = (unsigned short*)(ws + 5832704); //  1048576  (~6.9MB)

    prep_kernel<<<320, 256, 0, stream>>>(hidden, W, bias, u, w2hi, w2lo);
    score_kernel<<<2048, 512, 0, stream>>>(enc, w2hi, w2lo, u, v, scores_part);
    ctx_partial_kernel<<<1024, 256, 0, stream>>>(enc, scores_part, partials);
    ctx_reduce_kernel<<<128, 256, 0, stream>>>(partials, out);
}